// Round 1
// baseline (205.293 us; speedup 1.0000x reference)
//
#include <hip/hip_runtime.h>
#include <hip/hip_bf16.h>
#include <stdint.h>
#include <stddef.h>

#define D_MODEL 4096
#define RANK    64
#define GROUPQ  32

typedef __attribute__((ext_vector_type(4)))  float f32x4;
typedef __attribute__((ext_vector_type(16))) float f32x16;
typedef __attribute__((ext_vector_type(8)))  short bf16x8;

// float -> bf16 bits, round-to-nearest-even (finite inputs only)
__device__ inline short f2bf(float f) {
    union { float f; uint32_t u; } c; c.f = f;
    uint32_t u = c.u;
    u += 0x7fffu + ((u >> 16) & 1u);
    return (short)(u >> 16);
}

// ---------------------------------------------------------------------------
// Kernel 1: dequantize both weight matrices to bf16 in workspace.
//   a_deq[r][d] = qa_vals[r][d] * qa_scales[r][d/32]      (RANK x D_MODEL)
//   b_deq[d][r] = qb_vals[d][r] * qb_scales[d][r/32]      (D_MODEL x RANK)
// ---------------------------------------------------------------------------
__global__ void dequant_kernel(const int* __restrict__ qa, const float* __restrict__ qas,
                               const int* __restrict__ qb, const float* __restrict__ qbs,
                               short* __restrict__ a_deq, short* __restrict__ b_deq) {
    int idx = blockIdx.x * 256 + threadIdx.x;
    if (idx >= RANK * D_MODEL) return;
    {   // a: idx = r*D + d
        int r = idx / D_MODEL, d = idx - r * D_MODEL;
        a_deq[idx] = f2bf((float)qa[idx] * qas[r * (D_MODEL / GROUPQ) + (d >> 5)]);
    }
    {   // b: idx = d*R + r
        int d = idx / RANK, r = idx - d * RANK;
        b_deq[idx] = f2bf((float)qb[idx] * qbs[d * (RANK / GROUPQ) + (r >> 5)]);
    }
}

// ---------------------------------------------------------------------------
// Kernel 2: h[T][RANK] = x[T][D] @ a_deq[RANK][D]^T   (bf16 out, fp32 accum)
// Block: 512 threads = 8 waves; block owns 16 output rows; wave w owns
// K-range [w*512, (w+1)*512). mfma 16x16x32 bf16, 4 N-tiles (RANK=64).
// Cross-wave reduction through LDS.
// ---------------------------------------------------------------------------
__global__ __launch_bounds__(512) void stage1_kernel(const float* __restrict__ x,
                                                     const short* __restrict__ a_deq,
                                                     short* __restrict__ h) {
    const int lane = threadIdx.x & 63;
    const int wave = threadIdx.x >> 6;
    const int base = blockIdx.x * 16;
    const int KW = D_MODEL / 8;          // 512 per wave
    const int k_begin = wave * KW;

    const int row  = base + (lane & 15);          // A-frag row (M)
    const int koff = (lane >> 4) * 8;             // A/B-frag k sub-offset

    const float* xp  = x + (size_t)row * D_MODEL + k_begin + koff;
    const short* ap0 = a_deq + (size_t)(lane & 15) * D_MODEL + k_begin + koff;

    f32x4 acc[4] = {{0.f,0.f,0.f,0.f},{0.f,0.f,0.f,0.f},
                    {0.f,0.f,0.f,0.f},{0.f,0.f,0.f,0.f}};

    #pragma unroll 4
    for (int kk = 0; kk < KW; kk += 32) {
        f32x4 xv0 = *(const f32x4*)(xp + kk);
        f32x4 xv1 = *(const f32x4*)(xp + kk + 4);
        bf16x8 af;
        #pragma unroll
        for (int j = 0; j < 4; j++) { af[j] = f2bf(xv0[j]); af[j + 4] = f2bf(xv1[j]); }
        #pragma unroll
        for (int n = 0; n < 4; n++) {
            bf16x8 bf = *(const bf16x8*)(ap0 + (size_t)n * 16 * D_MODEL + kk);
            acc[n] = __builtin_amdgcn_mfma_f32_16x16x32_bf16(af, bf, acc[n], 0, 0, 0);
        }
    }

    // reduce the 8 waves' partial 16x64 tiles
    __shared__ float red[8][16][64];   // 32 KB
    #pragma unroll
    for (int n = 0; n < 4; n++)
        #pragma unroll
        for (int j = 0; j < 4; j++)
            red[wave][(lane >> 4) * 4 + j][n * 16 + (lane & 15)] = acc[n][j];
    __syncthreads();

    for (int e = threadIdx.x; e < 16 * 64; e += 512) {
        int r0 = e >> 6, c0 = e & 63;
        float s = 0.f;
        #pragma unroll
        for (int w = 0; w < 8; w++) s += red[w][r0][c0];
        h[(size_t)(base + r0) * RANK + c0] = f2bf(s);
    }
}

// ---------------------------------------------------------------------------
// Kernel 3: out[T][D] = h[T][RANK] @ b_deq[D][RANK]^T   (fp32 out)
// mfma 32x32x16 bf16. Wave: 32 rows x 128 cols (4 tiles). Block: 4 waves
// side-by-side in N -> 32 rows x 512 cols. Grid (T/32, D/512).
// C layout: col = lane&31, row = (reg&3) + 8*(reg>>2) + 4*(lane>>5)
//  -> each store instruction writes 2 x 128B contiguous segments.
// ---------------------------------------------------------------------------
__global__ __launch_bounds__(256) void stage2_kernel(const short* __restrict__ h,
                                                     const short* __restrict__ b_deq,
                                                     float* __restrict__ out) {
    const int lane = threadIdx.x & 63;
    const int wave = threadIdx.x >> 6;
    const int rb = blockIdx.x * 32;
    const int cb = blockIdx.y * 512 + wave * 128;
    const int koff = (lane >> 5) * 8;

    const short* hp = h + (size_t)(rb + (lane & 31)) * RANK + koff;
    const short* bp = b_deq + (size_t)(cb + (lane & 31)) * RANK + koff;

    f32x16 acc[4];
    #pragma unroll
    for (int t = 0; t < 4; t++)
        #pragma unroll
        for (int j = 0; j < 16; j++) acc[t][j] = 0.f;

    #pragma unroll
    for (int k0 = 0; k0 < RANK; k0 += 16) {
        bf16x8 af = *(const bf16x8*)(hp + k0);
        #pragma unroll
        for (int t = 0; t < 4; t++) {
            bf16x8 bf = *(const bf16x8*)(bp + (size_t)t * 32 * RANK + k0);
            acc[t] = __builtin_amdgcn_mfma_f32_32x32x16_bf16(af, bf, acc[t], 0, 0, 0);
        }
    }

    #pragma unroll
    for (int t = 0; t < 4; t++) {
        #pragma unroll
        for (int reg = 0; reg < 16; reg++) {
            int r = (reg & 3) + 8 * (reg >> 2) + 4 * (lane >> 5);
            int c = cb + t * 32 + (lane & 31);
            out[(size_t)(rb + r) * D_MODEL + c] = acc[t][reg];
        }
    }
}

// ---------------------------------------------------------------------------
extern "C" void kernel_launch(void* const* d_in, const int* in_sizes, int n_in,
                              void* d_out, int out_size, void* d_ws, size_t ws_size,
                              hipStream_t stream) {
    (void)n_in; (void)out_size; (void)ws_size;
    const float* x   = (const float*)d_in[0];
    const int*   qa  = (const int*)d_in[1];
    const float* qas = (const float*)d_in[2];
    const int*   qb  = (const int*)d_in[3];
    const float* qbs = (const float*)d_in[4];
    float* out = (float*)d_out;

    const int T = in_sizes[0] / D_MODEL;   // 16384

    // workspace layout (shorts): a_deq [64*4096], b_deq [4096*64], h [T*64]
    short* a_deq = (short*)d_ws;
    short* b_deq = a_deq + (size_t)RANK * D_MODEL;
    short* h     = b_deq + (size_t)D_MODEL * RANK;

    dequant_kernel<<<(RANK * D_MODEL + 255) / 256, 256, 0, stream>>>(qa, qas, qb, qbs,
                                                                     a_deq, b_deq);
    stage1_kernel<<<T / 16, 512, 0, stream>>>(x, a_deq, h);
    dim3 g2(T / 32, D_MODEL / 512);
    stage2_kernel<<<g2, 256, 0, stream>>>(h, b_deq, out);
}

// Round 2
// 159.756 us; speedup vs baseline: 1.2850x; 1.2850x over previous
//
#include <hip/hip_runtime.h>
#include <hip/hip_bf16.h>
#include <stdint.h>
#include <stddef.h>

#define D_MODEL 4096
#define RANK    64
#define GROUPQ  32
#define M_BLK   32
#define KC      512                 // fp32 elements per K-chunk
#define NCHUNK  (D_MODEL / KC)      // 8

typedef __attribute__((ext_vector_type(4)))  float f32x4;
typedef __attribute__((ext_vector_type(16))) float f32x16;
typedef __attribute__((ext_vector_type(8)))  short bf16x8;

// float -> bf16 bits, round-to-nearest-even (finite inputs only)
__device__ inline short f2bf(float f) {
    union { float f; uint32_t u; } c; c.f = f;
    uint32_t u = c.u;
    u += 0x7fffu + ((u >> 16) & 1u);
    return (short)(u >> 16);
}

// ---------------------------------------------------------------------------
// Kernel 1: dequantize both weight matrices to bf16 in workspace.
// ---------------------------------------------------------------------------
__global__ void dequant_kernel(const int* __restrict__ qa, const float* __restrict__ qas,
                               const int* __restrict__ qb, const float* __restrict__ qbs,
                               short* __restrict__ a_deq, short* __restrict__ b_deq) {
    int idx = blockIdx.x * 256 + threadIdx.x;
    if (idx >= RANK * D_MODEL) return;
    {   // a: idx = r*D + d
        int r = idx / D_MODEL, d = idx - r * D_MODEL;
        a_deq[idx] = f2bf((float)qa[idx] * qas[r * (D_MODEL / GROUPQ) + (d >> 5)]);
    }
    {   // b: idx = d*R + r
        int d = idx / RANK, r = idx - d * RANK;
        b_deq[idx] = f2bf((float)qb[idx] * qbs[d * (RANK / GROUPQ) + (r >> 5)]);
    }
}

// ---------------------------------------------------------------------------
// Fused kernel: block = 32 token rows, 512 threads (8 waves).
// Phase 1: h[32][64] = x[32][4096] @ a^T via K-chunked LDS staging (bf16,
//          XOR-swizzled), 8-wave split-K, register prefetch of next chunk.
// Phase 2: cross-wave fp32 reduction -> h in LDS (bf16).
// Phase 3: out[32][4096] = h @ b^T, wave w owns cols [w*512, w*512+512).
// h never touches HBM.
// ---------------------------------------------------------------------------
__global__ __launch_bounds__(512) void fused_kernel(const float* __restrict__ x,
                                                    const short* __restrict__ a_deq,
                                                    const short* __restrict__ b_deq,
                                                    float* __restrict__ out) {
    // LDS: stage (32x512 bf16 = 32768 B) unioned with red (4x32x68 f32 = 34816 B),
    // then h_lds (32x80 bf16 = 5120 B).
    __shared__ __align__(16) char smem[34816 + 5120];
    short* stage = (short*)smem;            (void)stage;
    float* red   = (float*)smem;
    short* h_lds = (short*)(smem + 34816);

    const int tid  = threadIdx.x;
    const int lane = tid & 63;
    const int wave = tid >> 6;
    const int rb   = blockIdx.x * M_BLK;

    // staging coords: round r covers rows r*4+srow, thread reads f32x4 at scol
    const int srow = tid >> 7;              // 0..3
    const int scol = (tid & 127) << 2;      // 0,4,...,508
    const float* xbase = x + (size_t)rb * D_MODEL;

    // prefetch chunk 0 into registers
    f32x4 xr[8];
    #pragma unroll
    for (int r = 0; r < 8; ++r)
        xr[r] = *(const f32x4*)(xbase + (size_t)(r * 4 + srow) * D_MODEL + scol);

    f32x4 acc1[2][4];
    #pragma unroll
    for (int m = 0; m < 2; ++m)
        #pragma unroll
        for (int n = 0; n < 4; ++n)
            acc1[m][n] = (f32x4){0.f, 0.f, 0.f, 0.f};

    for (int c = 0; c < NCHUNK; ++c) {
        __syncthreads();   // previous chunk's LDS reads complete
        // convert + swizzled LDS write of chunk c
        #pragma unroll
        for (int r = 0; r < 8; ++r) {
            int row  = r * 4 + srow;
            int byte = row * 1024 + (scol << 1);
            byte ^= (row & 7) << 4;
            union { short s[4]; uint2 u; } p;
            #pragma unroll
            for (int j = 0; j < 4; ++j) p.s[j] = f2bf(xr[r][j]);
            *(uint2*)(smem + byte) = p.u;
        }
        // issue prefetch of chunk c+1 (hides under MFMA below)
        if (c + 1 < NCHUNK) {
            #pragma unroll
            for (int r = 0; r < 8; ++r)
                xr[r] = *(const f32x4*)(xbase + (size_t)(r * 4 + srow) * D_MODEL
                                        + (c + 1) * KC + scol);
        }
        __syncthreads();   // stage ready
        // MFMA: wave's k-slice [wave*64, wave*64+64) of this chunk
        #pragma unroll
        for (int ks = 0; ks < 2; ++ks) {
            const int kin = wave * 64 + ks * 32 + ((lane >> 4) << 3);
            bf16x8 afrag[2];
            #pragma unroll
            for (int m = 0; m < 2; ++m) {
                int row  = m * 16 + (lane & 15);
                int byte = row * 1024 + (kin << 1);
                byte ^= (row & 7) << 4;
                afrag[m] = *(const bf16x8*)(smem + byte);
            }
            const short* ap = a_deq + (size_t)(lane & 15) * D_MODEL + c * KC + kin;
            #pragma unroll
            for (int n = 0; n < 4; ++n) {
                bf16x8 bfrag = *(const bf16x8*)(ap + (size_t)n * 16 * D_MODEL);
                #pragma unroll
                for (int m = 0; m < 2; ++m)
                    acc1[m][n] = __builtin_amdgcn_mfma_f32_16x16x32_bf16(
                        afrag[m], bfrag, acc1[m][n], 0, 0, 0);
            }
        }
    }

    // ---- cross-wave reduction (stage memory reused as red) ----
    __syncthreads();                       // all stage reads done
    const int r4 = (lane >> 4) << 2;       // C-layout row group
    if (wave < 4) {
        #pragma unroll
        for (int m = 0; m < 2; ++m)
            #pragma unroll
            for (int n = 0; n < 4; ++n)
                #pragma unroll
                for (int j = 0; j < 4; ++j)
                    red[(wave * 32 + m * 16 + r4 + j) * 68 + n * 16 + (lane & 15)] =
                        acc1[m][n][j];
    }
    __syncthreads();
    if (wave >= 4) {
        #pragma unroll
        for (int m = 0; m < 2; ++m)
            #pragma unroll
            for (int n = 0; n < 4; ++n)
                #pragma unroll
                for (int j = 0; j < 4; ++j)
                    red[((wave - 4) * 32 + m * 16 + r4 + j) * 68 + n * 16 + (lane & 15)] +=
                        acc1[m][n][j];
    }
    __syncthreads();
    for (int e = tid; e < 32 * 64; e += 512) {
        int r = e >> 6, cc = e & 63;
        float s = red[(0 * 32 + r) * 68 + cc] + red[(1 * 32 + r) * 68 + cc]
                + red[(2 * 32 + r) * 68 + cc] + red[(3 * 32 + r) * 68 + cc];
        h_lds[r * 80 + cc] = f2bf(s);
    }
    __syncthreads();

    // ---- phase 3: out[32][4096] = h @ b^T; wave w -> cols [w*512, +512) ----
    bf16x8 hfrag[4];
    #pragma unroll
    for (int ks = 0; ks < 4; ++ks)
        hfrag[ks] = *(const bf16x8*)(h_lds + (lane & 31) * 80 + ks * 16 + ((lane >> 5) << 3));

    const int colbase = wave * 512;
    #pragma unroll
    for (int n = 0; n < 16; ++n) {
        const int col = colbase + n * 32 + (lane & 31);
        const short* bp = b_deq + (size_t)col * RANK + ((lane >> 5) << 3);
        f32x16 a2;
        #pragma unroll
        for (int j = 0; j < 16; ++j) a2[j] = 0.f;
        #pragma unroll
        for (int ks = 0; ks < 4; ++ks) {
            bf16x8 bfrag = *(const bf16x8*)(bp + ks * 16);
            a2 = __builtin_amdgcn_mfma_f32_32x32x16_bf16(hfrag[ks], bfrag, a2, 0, 0, 0);
        }
        #pragma unroll
        for (int reg = 0; reg < 16; ++reg) {
            int r = (reg & 3) + 8 * (reg >> 2) + ((lane >> 5) << 2);
            out[(size_t)(rb + r) * D_MODEL + col] = a2[reg];
        }
    }
}

// ---------------------------------------------------------------------------
extern "C" void kernel_launch(void* const* d_in, const int* in_sizes, int n_in,
                              void* d_out, int out_size, void* d_ws, size_t ws_size,
                              hipStream_t stream) {
    (void)n_in; (void)out_size; (void)ws_size;
    const float* x   = (const float*)d_in[0];
    const int*   qa  = (const int*)d_in[1];
    const float* qas = (const float*)d_in[2];
    const int*   qb  = (const int*)d_in[3];
    const float* qbs = (const float*)d_in[4];
    float* out = (float*)d_out;

    const int T = in_sizes[0] / D_MODEL;   // 16384

    short* a_deq = (short*)d_ws;                       // [64][4096] bf16
    short* b_deq = a_deq + (size_t)RANK * D_MODEL;     // [4096][64] bf16

    dequant_kernel<<<(RANK * D_MODEL + 255) / 256, 256, 0, stream>>>(qa, qas, qb, qbs,
                                                                     a_deq, b_deq);
    fused_kernel<<<T / M_BLK, 512, 0, stream>>>(x, a_deq, b_deq, out);
}